// Round 1
// baseline (9780.605 us; speedup 1.0000x reference)
//
#include <hip/hip_runtime.h>
#include <math.h>

// Problem constants (match reference)
constexpr int kN    = 100000;   // nodes
constexpr int kE    = 3200000;  // edges
constexpr int kDin  = 12;
constexpr int kHid  = 1024;
constexpr int kZrow = 12;       // z row padded 10 -> 12 floats for 16B alignment

// ---------------------------------------------------------------------------
// Kernel 1: per-node MLP + derived columns.
// z[n] = [ (relu(f@W1+b1)@W2+b2)[0..7], ymin_diff, intersection, 0, 0 ]
// Weights read with wave-uniform indices -> scalar loads (s_load), cached.
// ---------------------------------------------------------------------------
__global__ __launch_bounds__(256) void mlp_kernel(
    const float* __restrict__ feat,
    const float* __restrict__ W1,
    const float* __restrict__ b1,
    const float* __restrict__ W2,
    const float* __restrict__ b2,
    float* __restrict__ z)
{
    int n = blockIdx.x * blockDim.x + threadIdx.x;
    if (n >= kN) return;

    const float4* fr = reinterpret_cast<const float4*>(feat + (size_t)n * kDin);
    float4 f0 = fr[0], f1 = fr[1], f2 = fr[2];
    float f[12] = {f0.x, f0.y, f0.z, f0.w,
                   f1.x, f1.y, f1.z, f1.w,
                   f2.x, f2.y, f2.z, f2.w};

    float acc[8];
    #pragma unroll
    for (int o = 0; o < 8; ++o) acc[o] = b2[o];

    #pragma unroll 4
    for (int k = 0; k < kHid; ++k) {
        float h = b1[k];
        #pragma unroll
        for (int d = 0; d < 12; ++d) h = fmaf(f[d], W1[d * kHid + k], h);
        h = fmaxf(h, 0.0f);
        #pragma unroll
        for (int o = 0; o < 8; ++o) acc[o] = fmaf(h, W2[k * 8 + o], acc[o]);
    }

    float ymin_diff = (f[2] - f[10]) * 10.0f;
    bool mask = (f[0] <= f[5]) && (f[1] >= f[4]) &&
                (f[2] <= f[11]) && (f[3] >= f[10]);
    float inter = mask ? 5.0f : -5.0f;   // 10*mask - 5

    float* zr = z + (size_t)n * kZrow;
    float4 z0 = {acc[0], acc[1], acc[2], acc[3]};
    float4 z1 = {acc[4], acc[5], acc[6], acc[7]};
    float4 z2 = {ymin_diff, inter, 0.0f, 0.0f};
    reinterpret_cast<float4*>(zr)[0] = z0;
    reinterpret_cast<float4*>(zr)[1] = z1;
    reinterpret_cast<float4*>(zr)[2] = z2;
}

// ---------------------------------------------------------------------------
// Kernel 2: one KENN layer over edges.
// g = [z[a](10) , z[b](10) , rel(2)]; t = signs*g; softmax(t);
// delta_i = softplus(w) * p_i/s * signs_i; atomically add delta[0:10] to
// zout[a], delta[10:20] to zout[b]. zin is the pre-layer snapshot.
// ---------------------------------------------------------------------------
__global__ __launch_bounds__(256) void edge_kernel(
    const float* __restrict__ zin,
    float* __restrict__ zout,
    const float* __restrict__ rel,
    const int* __restrict__ sx,
    const int* __restrict__ sy,
    const float* __restrict__ cw,
    int layer)
{
    int e = blockIdx.x * blockDim.x + threadIdx.x;
    if (e >= kE) return;

    float w  = cw[layer];
    float sw = fmaxf(w, 0.0f) + log1pf(__expf(-fabsf(w)));  // stable softplus

    int a = sx[e];
    int b = sy[e];
    float2 r = reinterpret_cast<const float2*>(rel)[e];

    const float* za = zin + (size_t)a * kZrow;
    const float* zb = zin + (size_t)b * kZrow;
    float4 a0 = reinterpret_cast<const float4*>(za)[0];
    float4 a1 = reinterpret_cast<const float4*>(za)[1];
    float2 a2 = reinterpret_cast<const float2*>(za + 8)[0];
    float4 b0 = reinterpret_cast<const float4*>(zb)[0];
    float4 b1v = reinterpret_cast<const float4*>(zb)[1];
    float2 b2v = reinterpret_cast<const float2*>(zb + 8)[0];

    // t[i] = sign_i * g_i, sign_i = +1 even, -1 odd
    float t[22];
    t[0]  =  a0.x;  t[1]  = -a0.y;  t[2]  =  a0.z;  t[3]  = -a0.w;
    t[4]  =  a1.x;  t[5]  = -a1.y;  t[6]  =  a1.z;  t[7]  = -a1.w;
    t[8]  =  a2.x;  t[9]  = -a2.y;
    t[10] =  b0.x;  t[11] = -b0.y;  t[12] =  b0.z;  t[13] = -b0.w;
    t[14] =  b1v.x; t[15] = -b1v.y; t[16] =  b1v.z; t[17] = -b1v.w;
    t[18] =  b2v.x; t[19] = -b2v.y;
    t[20] =  r.x;   t[21] = -r.y;

    float m = t[0];
    #pragma unroll
    for (int i = 1; i < 22; ++i) m = fmaxf(m, t[i]);

    float p[22];
    float s = 0.0f;
    #pragma unroll
    for (int i = 0; i < 22; ++i) { p[i] = __expf(t[i] - m); s += p[i]; }

    float scale = sw / s;

    float* oa = zout + (size_t)a * kZrow;
    float* ob = zout + (size_t)b * kZrow;
    #pragma unroll
    for (int i = 0; i < 10; ++i) {
        float d = ((i & 1) ? -scale : scale) * p[i];
        unsafeAtomicAdd(oa + i, d);
    }
    #pragma unroll
    for (int i = 0; i < 10; ++i) {
        float d = ((i & 1) ? -scale : scale) * p[10 + i];
        unsafeAtomicAdd(ob + i, d);
    }
}

// ---------------------------------------------------------------------------
// Kernel 3: output heads. za = z[:,0:4], zb = z[:,4:8]; softmax each.
// Output layout (flat concat): za (N*4) | softmax(za) | zb | softmax(zb)
// ---------------------------------------------------------------------------
__global__ __launch_bounds__(256) void out_kernel(
    const float* __restrict__ z,
    float* __restrict__ out)
{
    int n = blockIdx.x * blockDim.x + threadIdx.x;
    if (n >= kN) return;

    const float* zr = z + (size_t)n * kZrow;
    float4 za = reinterpret_cast<const float4*>(zr)[0];
    float4 zb = reinterpret_cast<const float4*>(zr)[1];

    float ma = fmaxf(fmaxf(za.x, za.y), fmaxf(za.z, za.w));
    float ea0 = __expf(za.x - ma), ea1 = __expf(za.y - ma);
    float ea2 = __expf(za.z - ma), ea3 = __expf(za.w - ma);
    float ia = 1.0f / (ea0 + ea1 + ea2 + ea3);
    float4 sma = {ea0 * ia, ea1 * ia, ea2 * ia, ea3 * ia};

    float mb = fmaxf(fmaxf(zb.x, zb.y), fmaxf(zb.z, zb.w));
    float eb0 = __expf(zb.x - mb), eb1 = __expf(zb.y - mb);
    float eb2 = __expf(zb.z - mb), eb3 = __expf(zb.w - mb);
    float ib = 1.0f / (eb0 + eb1 + eb2 + eb3);
    float4 smb = {eb0 * ib, eb1 * ib, eb2 * ib, eb3 * ib};

    reinterpret_cast<float4*>(out)[n]            = za;
    reinterpret_cast<float4*>(out + 4 * kN)[n]   = sma;
    reinterpret_cast<float4*>(out + 8 * kN)[n]   = zb;
    reinterpret_cast<float4*>(out + 12 * kN)[n]  = smb;
}

// ---------------------------------------------------------------------------
extern "C" void kernel_launch(void* const* d_in, const int* in_sizes, int n_in,
                              void* d_out, int out_size, void* d_ws, size_t ws_size,
                              hipStream_t stream)
{
    // setup_inputs() dict order:
    const float* feat = (const float*)d_in[0];  // features (N,12)
    const float* rel  = (const float*)d_in[1];  // relations (E,2)
    const float* W1   = (const float*)d_in[2];  // (12,1024)
    const float* b1   = (const float*)d_in[3];  // (1024,)
    const float* W2   = (const float*)d_in[4];  // (1024,8)
    const float* b2   = (const float*)d_in[5];  // (8,)
    const float* cw   = (const float*)d_in[6];  // clause_w (3,)
    const int*   sx   = (const int*)d_in[7];    // (E,)
    const int*   sy   = (const int*)d_in[8];    // (E,)
    float* out = (float*)d_out;

    float* zA = (float*)d_ws;                   // N*12 floats
    float* zB = zA + (size_t)kN * kZrow;        // N*12 floats
    size_t zbytes = (size_t)kN * kZrow * sizeof(float);

    dim3 blk(256);
    dim3 gN((kN + 255) / 256);
    dim3 gE((kE + 255) / 256);

    mlp_kernel<<<gN, blk, 0, stream>>>(feat, W1, b1, W2, b2, zA);

    // layer 0: read zA, accumulate into zB (= copy of zA)
    hipMemcpyAsync(zB, zA, zbytes, hipMemcpyDeviceToDevice, stream);
    edge_kernel<<<gE, blk, 0, stream>>>(zA, zB, rel, sx, sy, cw, 0);

    // layer 1: read zB, accumulate into zA
    hipMemcpyAsync(zA, zB, zbytes, hipMemcpyDeviceToDevice, stream);
    edge_kernel<<<gE, blk, 0, stream>>>(zB, zA, rel, sx, sy, cw, 1);

    // layer 2: read zA, accumulate into zB
    hipMemcpyAsync(zB, zA, zbytes, hipMemcpyDeviceToDevice, stream);
    edge_kernel<<<gE, blk, 0, stream>>>(zA, zB, rel, sx, sy, cw, 2);

    out_kernel<<<gN, blk, 0, stream>>>(zB, out);
}

// Round 2
// 1366.645 us; speedup vs baseline: 7.1567x; 7.1567x over previous
//
#include <hip/hip_runtime.h>
#include <math.h>

// Problem constants (match reference)
constexpr int kN    = 100000;   // nodes
constexpr int kE    = 3200000;  // edges
constexpr int kHid  = 1024;
constexpr int kZrow = 12;       // z row padded 10 -> 12 floats (48 B)
constexpr int kCap  = 160;      // max incidences/node; deg ~ Poisson(64), P(>=160) ~ 1e-22

// ---------------------------------------------------------------------------
// Kernel 1: per-node MLP + derived columns.
// ---------------------------------------------------------------------------
__global__ __launch_bounds__(256) void mlp_kernel(
    const float* __restrict__ feat,
    const float* __restrict__ W1,
    const float* __restrict__ b1,
    const float* __restrict__ W2,
    const float* __restrict__ b2,
    float* __restrict__ z)
{
    int n = blockIdx.x * blockDim.x + threadIdx.x;
    if (n >= kN) return;

    const float4* fr = reinterpret_cast<const float4*>(feat + (size_t)n * 12);
    float4 f0 = fr[0], f1 = fr[1], f2 = fr[2];
    float f[12] = {f0.x, f0.y, f0.z, f0.w,
                   f1.x, f1.y, f1.z, f1.w,
                   f2.x, f2.y, f2.z, f2.w};

    float acc[8];
    #pragma unroll
    for (int o = 0; o < 8; ++o) acc[o] = b2[o];

    #pragma unroll 4
    for (int k = 0; k < kHid; ++k) {
        float h = b1[k];
        #pragma unroll
        for (int d = 0; d < 12; ++d) h = fmaf(f[d], W1[d * kHid + k], h);
        h = fmaxf(h, 0.0f);
        #pragma unroll
        for (int o = 0; o < 8; ++o) acc[o] = fmaf(h, W2[k * 8 + o], acc[o]);
    }

    float ymin_diff = (f[2] - f[10]) * 10.0f;
    bool mask = (f[0] <= f[5]) && (f[1] >= f[4]) &&
                (f[2] <= f[11]) && (f[3] >= f[10]);
    float inter = mask ? 5.0f : -5.0f;

    float* zr = z + (size_t)n * kZrow;
    reinterpret_cast<float4*>(zr)[0] = {acc[0], acc[1], acc[2], acc[3]};
    reinterpret_cast<float4*>(zr)[1] = {acc[4], acc[5], acc[6], acc[7]};
    reinterpret_cast<float4*>(zr)[2] = {ymin_diff, inter, 0.0f, 0.0f};
}

// ---------------------------------------------------------------------------
// Kernel 2: build fixed-capacity adjacency. For each edge e=(a,b):
//   node a gets entry {partner=b, e*2+0}; node b gets {partner=a, e*2+1}.
// 6.4M int atomics total (vs 192M fp atomics in the old path).
// ---------------------------------------------------------------------------
__global__ __launch_bounds__(256) void build_adj(
    const int* __restrict__ sx,
    const int* __restrict__ sy,
    int* __restrict__ deg,
    uint2* __restrict__ adj)
{
    int e = blockIdx.x * blockDim.x + threadIdx.x;
    if (e >= kE) return;
    int a = sx[e];
    int b = sy[e];
    int sa = atomicAdd(&deg[a], 1);
    if (sa < kCap) adj[(size_t)a * kCap + sa] = {(unsigned)b, (unsigned)(e << 1)};
    int sb = atomicAdd(&deg[b], 1);
    if (sb < kCap) adj[(size_t)b * kCap + sb] = {(unsigned)a, (unsigned)(e << 1) | 1u};
}

// ---------------------------------------------------------------------------
// Kernel 3: one KENN layer as a pure gather. 16-lane group per node; each
// lane recomputes full edge softmax for its incident entries; register
// accumulate; butterfly reduce over the group; single row write. No atomics.
// ---------------------------------------------------------------------------
__global__ __launch_bounds__(256) void kenn_gather(
    const float* __restrict__ zin,
    float* __restrict__ zout,
    const float* __restrict__ rel,
    const int* __restrict__ deg,
    const uint2* __restrict__ adj,
    const float* __restrict__ cw,
    int layer)
{
    int node = blockIdx.x * 16 + (threadIdx.x >> 4);   // 16 nodes / block
    int lane = threadIdx.x & 15;
    if (node >= kN) return;

    float w  = cw[layer];
    float sw = fmaxf(w, 0.0f) + log1pf(__expf(-fabsf(w)));  // softplus

    const float* zs = zin + (size_t)node * kZrow;
    float4 s0 = reinterpret_cast<const float4*>(zs)[0];
    float4 s1 = reinterpret_cast<const float4*>(zs)[1];
    float4 s2 = reinterpret_cast<const float4*>(zs)[2];   // cols 8..11
    float self[10] = {s0.x, s0.y, s0.z, s0.w, s1.x, s1.y, s1.z, s1.w, s2.x, s2.y};

    float acc[10] = {0, 0, 0, 0, 0, 0, 0, 0, 0, 0};
    int d = min(deg[node], kCap);

    for (int i = lane; i < d; i += 16) {
        uint2 ent = adj[(size_t)node * kCap + i];
        int p       = (int)ent.x;
        int e       = (int)(ent.y >> 1);
        bool second = (ent.y & 1u) != 0;   // this node is the sy endpoint

        float2 r = reinterpret_cast<const float2*>(rel)[e];
        const float* zp = zin + (size_t)p * kZrow;
        float4 p0 = reinterpret_cast<const float4*>(zp)[0];
        float4 p1 = reinterpret_cast<const float4*>(zp)[1];
        float2 p2 = reinterpret_cast<const float2*>(zp + 8)[0];
        float part[10] = {p0.x, p0.y, p0.z, p0.w, p1.x, p1.y, p1.z, p1.w, p2.x, p2.y};

        // g = [z[sx]; z[sy]; rel]; t = signs*g (sign_i = +1 even, -1 odd)
        float t[22];
        #pragma unroll
        for (int j = 0; j < 10; ++j) {
            float ga = second ? part[j] : self[j];   // x-endpoint value
            float gb = second ? self[j] : part[j];   // y-endpoint value
            t[j]      = (j & 1) ? -ga : ga;
            t[10 + j] = (j & 1) ? -gb : gb;
        }
        t[20] = r.x;
        t[21] = -r.y;

        float m = t[0];
        #pragma unroll
        for (int j = 1; j < 22; ++j) m = fmaxf(m, t[j]);

        float pe[22];
        float ssum = 0.0f;
        #pragma unroll
        for (int j = 0; j < 22; ++j) { pe[j] = __expf(t[j] - m); ssum += pe[j]; }

        float scale = sw / ssum;
        #pragma unroll
        for (int j = 0; j < 10; ++j) {
            float pv = second ? pe[10 + j] : pe[j];  // take the half for OUR side
            acc[j] += ((j & 1) ? -scale : scale) * pv;
        }
    }

    #pragma unroll
    for (int m16 = 8; m16 >= 1; m16 >>= 1) {
        #pragma unroll
        for (int j = 0; j < 10; ++j)
            acc[j] += __shfl_xor(acc[j], m16, 16);
    }

    if (lane == 0) {
        float* zo = zout + (size_t)node * kZrow;
        reinterpret_cast<float4*>(zo)[0] =
            {self[0] + acc[0], self[1] + acc[1], self[2] + acc[2], self[3] + acc[3]};
        reinterpret_cast<float4*>(zo)[1] =
            {self[4] + acc[4], self[5] + acc[5], self[6] + acc[6], self[7] + acc[7]};
        reinterpret_cast<float4*>(zo)[2] =
            {self[8] + acc[8], self[9] + acc[9], s2.z, s2.w};
    }
}

// ---------------------------------------------------------------------------
// Kernel 4: output heads.
// ---------------------------------------------------------------------------
__global__ __launch_bounds__(256) void out_kernel(
    const float* __restrict__ z,
    float* __restrict__ out)
{
    int n = blockIdx.x * blockDim.x + threadIdx.x;
    if (n >= kN) return;

    const float* zr = z + (size_t)n * kZrow;
    float4 za = reinterpret_cast<const float4*>(zr)[0];
    float4 zb = reinterpret_cast<const float4*>(zr)[1];

    float ma = fmaxf(fmaxf(za.x, za.y), fmaxf(za.z, za.w));
    float ea0 = __expf(za.x - ma), ea1 = __expf(za.y - ma);
    float ea2 = __expf(za.z - ma), ea3 = __expf(za.w - ma);
    float ia = 1.0f / (ea0 + ea1 + ea2 + ea3);
    float4 sma = {ea0 * ia, ea1 * ia, ea2 * ia, ea3 * ia};

    float mb = fmaxf(fmaxf(zb.x, zb.y), fmaxf(zb.z, zb.w));
    float eb0 = __expf(zb.x - mb), eb1 = __expf(zb.y - mb);
    float eb2 = __expf(zb.z - mb), eb3 = __expf(zb.w - mb);
    float ib = 1.0f / (eb0 + eb1 + eb2 + eb3);
    float4 smb = {eb0 * ib, eb1 * ib, eb2 * ib, eb3 * ib};

    reinterpret_cast<float4*>(out)[n]           = za;
    reinterpret_cast<float4*>(out + 4 * kN)[n]  = sma;
    reinterpret_cast<float4*>(out + 8 * kN)[n]  = zb;
    reinterpret_cast<float4*>(out + 12 * kN)[n] = smb;
}

// ---------------------------------------------------------------------------
// Fallback (R1 path): atomic scatter edge kernel, used only if ws too small.
// ---------------------------------------------------------------------------
__global__ __launch_bounds__(256) void edge_kernel(
    const float* __restrict__ zin,
    float* __restrict__ zout,
    const float* __restrict__ rel,
    const int* __restrict__ sx,
    const int* __restrict__ sy,
    const float* __restrict__ cw,
    int layer)
{
    int e = blockIdx.x * blockDim.x + threadIdx.x;
    if (e >= kE) return;

    float w  = cw[layer];
    float sw = fmaxf(w, 0.0f) + log1pf(__expf(-fabsf(w)));

    int a = sx[e];
    int b = sy[e];
    float2 r = reinterpret_cast<const float2*>(rel)[e];

    const float* za = zin + (size_t)a * kZrow;
    const float* zb = zin + (size_t)b * kZrow;
    float4 a0 = reinterpret_cast<const float4*>(za)[0];
    float4 a1 = reinterpret_cast<const float4*>(za)[1];
    float2 a2 = reinterpret_cast<const float2*>(za + 8)[0];
    float4 b0 = reinterpret_cast<const float4*>(zb)[0];
    float4 b1v = reinterpret_cast<const float4*>(zb)[1];
    float2 b2v = reinterpret_cast<const float2*>(zb + 8)[0];

    float t[22];
    t[0]  =  a0.x;  t[1]  = -a0.y;  t[2]  =  a0.z;  t[3]  = -a0.w;
    t[4]  =  a1.x;  t[5]  = -a1.y;  t[6]  =  a1.z;  t[7]  = -a1.w;
    t[8]  =  a2.x;  t[9]  = -a2.y;
    t[10] =  b0.x;  t[11] = -b0.y;  t[12] =  b0.z;  t[13] = -b0.w;
    t[14] =  b1v.x; t[15] = -b1v.y; t[16] =  b1v.z; t[17] = -b1v.w;
    t[18] =  b2v.x; t[19] = -b2v.y;
    t[20] =  r.x;   t[21] = -r.y;

    float m = t[0];
    #pragma unroll
    for (int i = 1; i < 22; ++i) m = fmaxf(m, t[i]);
    float p[22]; float s = 0.0f;
    #pragma unroll
    for (int i = 0; i < 22; ++i) { p[i] = __expf(t[i] - m); s += p[i]; }
    float scale = sw / s;

    float* oa = zout + (size_t)a * kZrow;
    float* ob = zout + (size_t)b * kZrow;
    #pragma unroll
    for (int i = 0; i < 10; ++i)
        unsafeAtomicAdd(oa + i, ((i & 1) ? -scale : scale) * p[i]);
    #pragma unroll
    for (int i = 0; i < 10; ++i)
        unsafeAtomicAdd(ob + i, ((i & 1) ? -scale : scale) * p[10 + i]);
}

// ---------------------------------------------------------------------------
extern "C" void kernel_launch(void* const* d_in, const int* in_sizes, int n_in,
                              void* d_out, int out_size, void* d_ws, size_t ws_size,
                              hipStream_t stream)
{
    const float* feat = (const float*)d_in[0];
    const float* rel  = (const float*)d_in[1];
    const float* W1   = (const float*)d_in[2];
    const float* b1   = (const float*)d_in[3];
    const float* W2   = (const float*)d_in[4];
    const float* b2   = (const float*)d_in[5];
    const float* cw   = (const float*)d_in[6];
    const int*   sx   = (const int*)d_in[7];
    const int*   sy   = (const int*)d_in[8];
    float* out = (float*)d_out;

    // ws layout: zA (4.8MB) | zB (4.8MB) | deg (400KB) | adj (128MB)
    char* ws = (char*)d_ws;
    float* zA  = (float*)ws;
    float* zB  = (float*)(ws + 4800000);
    int*   deg = (int*)  (ws + 9600000);
    uint2* adj = (uint2*)(ws + 10000000);
    size_t need = 10000000 + (size_t)kN * kCap * sizeof(uint2);

    dim3 blk(256);
    dim3 gN((kN + 255) / 256);
    dim3 gE((kE + 255) / 256);
    dim3 gG(kN / 16);              // 100000/16 = 6250 exactly

    mlp_kernel<<<gN, blk, 0, stream>>>(feat, W1, b1, W2, b2, zA);

    if (ws_size >= need) {
        hipMemsetAsync(deg, 0, kN * sizeof(int), stream);
        build_adj<<<gE, blk, 0, stream>>>(sx, sy, deg, adj);
        kenn_gather<<<gG, blk, 0, stream>>>(zA, zB, rel, deg, adj, cw, 0);
        kenn_gather<<<gG, blk, 0, stream>>>(zB, zA, rel, deg, adj, cw, 1);
        kenn_gather<<<gG, blk, 0, stream>>>(zA, zB, rel, deg, adj, cw, 2);
        out_kernel<<<gN, blk, 0, stream>>>(zB, out);
    } else {
        // fallback: R1 atomic path
        size_t zbytes = (size_t)kN * kZrow * sizeof(float);
        hipMemcpyAsync(zB, zA, zbytes, hipMemcpyDeviceToDevice, stream);
        edge_kernel<<<gE, blk, 0, stream>>>(zA, zB, rel, sx, sy, cw, 0);
        hipMemcpyAsync(zA, zB, zbytes, hipMemcpyDeviceToDevice, stream);
        edge_kernel<<<gE, blk, 0, stream>>>(zB, zA, rel, sx, sy, cw, 1);
        hipMemcpyAsync(zB, zA, zbytes, hipMemcpyDeviceToDevice, stream);
        edge_kernel<<<gE, blk, 0, stream>>>(zA, zB, rel, sx, sy, cw, 2);
        out_kernel<<<gN, blk, 0, stream>>>(zB, out);
    }
}